// Round 1
// baseline (944.444 us; speedup 1.0000x reference)
//
#include <hip/hip_runtime.h>
#include <stdint.h>

typedef __attribute__((ext_vector_type(8))) short short8;
typedef __attribute__((ext_vector_type(4))) float f32x4;
typedef unsigned short u16;

// ---- helpers ----
__device__ __forceinline__ u16 f2bf(float f) {
  uint32_t u = __builtin_bit_cast(uint32_t, f);
  u = (u + 0x7FFFu + ((u >> 16) & 1u)) >> 16;
  return (u16)u;
}
__device__ __forceinline__ float bf2f(u16 h) {
  uint32_t u = ((uint32_t)h) << 16;
  return __builtin_bit_cast(float, u);
}
__device__ __forceinline__ void lds16(const u16* g, u16* l) {
  __builtin_amdgcn_global_load_lds(
      (const __attribute__((address_space(1))) void*)g,
      (__attribute__((address_space(3))) void*)l, 16, 0, 0);
}

// ---- split f32 -> bf16 hi (+ optional lo) ----
__global__ void split_kernel(const float* __restrict__ in, u16* __restrict__ hi,
                             u16* __restrict__ lo, int n) {
  int i = blockIdx.x * blockDim.x + threadIdx.x;
  int stride = gridDim.x * blockDim.x;
  for (; i < n; i += stride) {
    float v = in[i];
    u16 h = f2bf(v);
    hi[i] = h;
    if (lo) lo[i] = f2bf(v - bf2f(h));
  }
}

// ---- GEMM: C[m][n] = sum_k A[m][k]*B[n][k]  (A: MxK, B: NxK, both row-major bf16)
// SPLIT=1: hi only. SPLIT=3: hi*hi + hi*lo + lo*hi (fp32-ish precision).
// EPI 0: bf16 (b,h,t,d) layout, *qscale    (Q)
// EPI 1: sign -> +-1 bf16, (b,h,t,d) layout (K,V)
// EPI 2: f32 row-major MxN                  (final out)
template<int SPLIT, int EPI>
__global__ __launch_bounds__(256) void gemm_bt(
    const u16* __restrict__ Ahi, const u16* __restrict__ Alo,
    const u16* __restrict__ Bhi, const u16* __restrict__ Blo,
    u16* __restrict__ outb, float* __restrict__ outf,
    int Mdim, int Ndim, int Kdim)
{
  __shared__ __align__(16) u16 sAh[128*32];
  __shared__ __align__(16) u16 sBh[128*32];
  __shared__ __align__(16) u16 sAl[(SPLIT>1)?128*32:8];
  __shared__ __align__(16) u16 sBl[(SPLIT>1)?128*32:8];
  const int t = threadIdx.x;
  const int l = t & 63, w = t >> 6;
  const int wm = w >> 1, wn = w & 1;
  const int m0 = blockIdx.y * 128, n0 = blockIdx.x * 128;
  const int srow = t >> 2, scol = (t & 3) * 8;
  const int fr = l & 15, fc8 = (l >> 4) * 8;

  f32x4 acc[4][4] = {};

  for (int k0 = 0; k0 < Kdim; k0 += 32) {
#pragma unroll
    for (int i = 0; i < 2; i++) {
      size_t ga = (size_t)(m0 + i*64 + srow) * Kdim + k0 + scol;
      size_t gb = (size_t)(n0 + i*64 + srow) * Kdim + k0 + scol;
      lds16(Ahi + ga, sAh + i*2048 + t*8);
      lds16(Bhi + gb, sBh + i*2048 + t*8);
      if constexpr (SPLIT > 1) {
        lds16(Alo + ga, sAl + i*2048 + t*8);
        lds16(Blo + gb, sBl + i*2048 + t*8);
      }
    }
    __syncthreads();
    short8 ah[4], bh[4], al[4], bl[4];
#pragma unroll
    for (int f = 0; f < 4; f++) {
      ah[f] = *(const short8*)(sAh + (wm*64 + f*16 + fr)*32 + fc8);
      bh[f] = *(const short8*)(sBh + (wn*64 + f*16 + fr)*32 + fc8);
      if constexpr (SPLIT > 1) {
        al[f] = *(const short8*)(sAl + (wm*64 + f*16 + fr)*32 + fc8);
        bl[f] = *(const short8*)(sBl + (wn*64 + f*16 + fr)*32 + fc8);
      }
    }
#pragma unroll
    for (int fm = 0; fm < 4; fm++)
#pragma unroll
      for (int fn = 0; fn < 4; fn++) {
        acc[fm][fn] = __builtin_amdgcn_mfma_f32_16x16x32_bf16(ah[fm], bh[fn], acc[fm][fn], 0, 0, 0);
        if constexpr (SPLIT > 1) {
          acc[fm][fn] = __builtin_amdgcn_mfma_f32_16x16x32_bf16(ah[fm], bl[fn], acc[fm][fn], 0, 0, 0);
          acc[fm][fn] = __builtin_amdgcn_mfma_f32_16x16x32_bf16(al[fm], bh[fn], acc[fm][fn], 0, 0, 0);
        }
      }
    __syncthreads();
  }

  const float qscale = 0.08838834764831843f; // 1/sqrt(128)
#pragma unroll
  for (int fm = 0; fm < 4; fm++)
#pragma unroll
    for (int fn = 0; fn < 4; fn++)
#pragma unroll
      for (int r = 0; r < 4; r++) {
        int gm = m0 + wm*64 + fm*16 + (l>>4)*4 + r;
        int gn = n0 + wn*64 + fn*16 + (l & 15);
        float val = acc[fm][fn][r];
        if constexpr (EPI == 2) {
          outf[(size_t)gm * Ndim + gn] = val;
        } else {
          int b = gm >> 12, tt = gm & 4095, h = gn >> 7, dd = gn & 127;
          size_t idx = (((size_t)(b*16 + h))*4096 + tt)*128 + dd;
          if constexpr (EPI == 0) outb[idx] = f2bf(val * qscale);
          else                    outb[idx] = (val >= 0.f) ? (u16)0x3F80 : (u16)0xBF80;
        }
      }
}

// ---- pack sign bits over chunk dim: word[d] bit c = sign(k[b,h,n*64+c,d]) ----
__global__ void pack_signs(const u16* __restrict__ k, const u16* __restrict__ v,
                           unsigned long long* __restrict__ kp, unsigned long long* __restrict__ vp) {
  const int blk = blockIdx.x;            // (b*16+h)*64 + n
  const int d = threadIdx.x;             // 0..127
  const int bh = blk >> 6, n = blk & 63;
  size_t base = (((size_t)bh * 4096) + n * 64) * 128 + d;
  unsigned long long kw = 0, vw = 0;
  for (int c = 0; c < 64; c++) {
    kw |= (unsigned long long)(k[base + (size_t)c*128] >> 15) << c;
    vw |= (unsigned long long)(v[base + (size_t)c*128] >> 15) << c;
  }
  kp[(size_t)blk * 128 + d] = kw;
  vp[(size_t)blk * 128 + d] = vw;
}

// ---- intra: per chunk, scores = Q Kc^T (masked), intra = scores Vc ----
__global__ __launch_bounds__(256) void intra_kernel(
    const u16* __restrict__ q, const u16* __restrict__ k,
    const unsigned long long* __restrict__ vp, u16* __restrict__ intra)
{
  __shared__ __align__(16) u16 sQ[64*128];
  __shared__ __align__(16) u16 sK[64*128];
  __shared__ __align__(16) u16 sS[64*64];
  __shared__ __align__(16) u16 sVt[128*64];
  const int t = threadIdx.x, l = t & 63, w = t >> 6;
  const int blk = blockIdx.x;            // (b*16+h)*64 + n
  const int bh = blk >> 6, n = blk & 63;
  const size_t qbase = (((size_t)bh * 4096) + n * 64) * 128;
#pragma unroll
  for (int i = 0; i < 4; i++) {
    size_t g = qbase + (size_t)(i*16 + (t>>4)) * 128 + (t & 15) * 8;
    lds16(q + g, sQ + i*2048 + t*8);
    lds16(k + g, sK + i*2048 + t*8);
  }
  { // unpack V^T (d-major) from bit words
    int d = t >> 1, ch = (t & 1) * 32;
    unsigned long long wv = vp[(size_t)blk * 128 + d];
#pragma unroll
    for (int c = 0; c < 32; c += 2) {
      uint32_t b0 = ((wv >> (ch + c)) & 1ull)     ? 0xBF80u : 0x3F80u;
      uint32_t b1 = ((wv >> (ch + c + 1)) & 1ull) ? 0xBF80u : 0x3F80u;
      ((uint32_t*)sVt)[(d*64 + ch + c) >> 1] = b0 | (b1 << 16);
    }
  }
  __syncthreads();

  const int fr = l & 15, fc8 = (l >> 4) * 8;
  f32x4 accS[4] = {};
#pragma unroll
  for (int kk = 0; kk < 4; kk++) {
    short8 a = *(const short8*)(sQ + (w*16 + fr)*128 + kk*32 + fc8);
#pragma unroll
    for (int fn = 0; fn < 4; fn++) {
      short8 bb = *(const short8*)(sK + (fn*16 + fr)*128 + kk*32 + fc8);
      accS[fn] = __builtin_amdgcn_mfma_f32_16x16x32_bf16(a, bb, accS[fn], 0, 0, 0);
    }
  }
#pragma unroll
  for (int fn = 0; fn < 4; fn++)
#pragma unroll
    for (int r = 0; r < 4; r++) {
      int i = w*16 + (l>>4)*4 + r;
      int j = fn*16 + (l & 15);
      float v = (j <= i) ? accS[fn][r] : 0.f;
      sS[i*64 + j] = f2bf(v);
    }
  __syncthreads();

  f32x4 accI[8] = {};
#pragma unroll
  for (int kk = 0; kk < 2; kk++) {
    short8 a = *(const short8*)(sS + (w*16 + fr)*64 + kk*32 + fc8);
#pragma unroll
    for (int fn = 0; fn < 8; fn++) {
      short8 bb = *(const short8*)(sVt + (fn*16 + fr)*64 + kk*32 + fc8);
      accI[fn] = __builtin_amdgcn_mfma_f32_16x16x32_bf16(a, bb, accI[fn], 0, 0, 0);
    }
  }
  const int b = bh >> 4, h = bh & 15;
#pragma unroll
  for (int fn = 0; fn < 8; fn++)
#pragma unroll
    for (int r = 0; r < 4; r++) {
      int c = w*16 + (l>>4)*4 + r;
      int dd = fn*16 + (l & 15);
      size_t idx = ((size_t)(b*4096 + n*64 + c)) * 2048 + h*128 + dd;
      intra[idx] = f2bf(accI[fn][r]);
    }
}

// ---- sequential state scan + cross term; writes att = intra+cross and final_state ----
__global__ __launch_bounds__(256) void state_cross(
    const u16* __restrict__ q, const unsigned long long* __restrict__ kp,
    const unsigned long long* __restrict__ vp, const u16* __restrict__ intra,
    u16* __restrict__ att, float* __restrict__ fstate)
{
  __shared__ __align__(16) u16 sQ[64*128];
  __shared__ __align__(16) u16 sB[32*128];
  __shared__ unsigned long long sKp[128];
  const int t = threadIdx.x, l = t & 63, w = t >> 6;
  const int bh = blockIdx.x >> 2, eq = blockIdx.x & 3;
  const int e0 = eq * 32;
  const int eloc = t >> 3;               // 0..31 (local e)
  const int d0 = (t & 7) * 16;           // this thread's 16 d's
  const int b = bh >> 4, h = bh & 15;
  const int fr = l & 15, fc8 = (l >> 4) * 8;
  int s[16];
#pragma unroll
  for (int i = 0; i < 16; i++) s[i] = 0;

  for (int n = 0; n < 64; n++) {
    const size_t pbase = ((size_t)bh * 64 + n) * 128;
#pragma unroll
    for (int i = 0; i < 4; i++) {
      size_t g = (((size_t)bh * 4096) + n*64 + i*16 + (t>>4)) * 128 + (t & 15) * 8;
      lds16(q + g, sQ + i*2048 + t*8);
    }
    if (t < 128) sKp[t] = kp[pbase + t];
    unsigned long long vw = vp[pbase + e0 + eloc];
    __syncthreads();

    f32x4 acch[2] = {}, accl[2] = {};
    if (n > 0) {
      // pass 1: hi = floor(state/32)
#pragma unroll
      for (int dd = 0; dd < 16; dd += 2) {
        uint32_t p = (uint32_t)f2bf((float)(s[dd] >> 5)) |
                     ((uint32_t)f2bf((float)(s[dd+1] >> 5)) << 16);
        ((uint32_t*)sB)[(eloc*128 + d0 + dd) >> 1] = p;
      }
      __syncthreads();
#pragma unroll
      for (int kk = 0; kk < 4; kk++) {
        short8 a = *(const short8*)(sQ + (w*16 + fr)*128 + kk*32 + fc8);
#pragma unroll
        for (int fn = 0; fn < 2; fn++) {
          short8 bb = *(const short8*)(sB + (fn*16 + fr)*128 + kk*32 + fc8);
          acch[fn] = __builtin_amdgcn_mfma_f32_16x16x32_bf16(a, bb, acch[fn], 0, 0, 0);
        }
      }
      __syncthreads();
      // pass 2: lo = state & 31
#pragma unroll
      for (int dd = 0; dd < 16; dd += 2) {
        uint32_t p = (uint32_t)f2bf((float)(s[dd] & 31)) |
                     ((uint32_t)f2bf((float)(s[dd+1] & 31)) << 16);
        ((uint32_t*)sB)[(eloc*128 + d0 + dd) >> 1] = p;
      }
      __syncthreads();
#pragma unroll
      for (int kk = 0; kk < 4; kk++) {
        short8 a = *(const short8*)(sQ + (w*16 + fr)*128 + kk*32 + fc8);
#pragma unroll
        for (int fn = 0; fn < 2; fn++) {
          short8 bb = *(const short8*)(sB + (fn*16 + fr)*128 + kk*32 + fc8);
          accl[fn] = __builtin_amdgcn_mfma_f32_16x16x32_bf16(a, bb, accl[fn], 0, 0, 0);
        }
      }
    }
    // att = intra + cross
#pragma unroll
    for (int fn = 0; fn < 2; fn++)
#pragma unroll
      for (int r = 0; r < 4; r++) {
        int c = w*16 + (l>>4)*4 + r;
        int dd = e0 + fn*16 + (l & 15);
        size_t idx = ((size_t)(b*4096 + n*64 + c)) * 2048 + h*128 + dd;
        att[idx] = f2bf(bf2f(intra[idx]) + 32.f * acch[fn][r] + accl[fn][r]);
      }
    // state += K^T V of this chunk (exact, via popcount)
#pragma unroll
    for (int dd = 0; dd < 16; dd++)
      s[dd] += 64 - 2 * __popcll(sKp[d0 + dd] ^ vw);
    __syncthreads();
  }
#pragma unroll
  for (int dd = 0; dd < 16; dd++)
    fstate[((size_t)bh * 128 + d0 + dd) * 128 + e0 + eloc] = (float)s[dd];
}

extern "C" void kernel_launch(void* const* d_in, const int* in_sizes, int n_in,
                              void* d_out, int out_size, void* d_ws, size_t ws_size,
                              hipStream_t stream) {
  (void)in_sizes; (void)n_in; (void)out_size; (void)ws_size;
  const float* x  = (const float*)d_in[0];
  const float* Wq = (const float*)d_in[1];
  const float* Wk = (const float*)d_in[2];
  const float* Wv = (const float*)d_in[3];
  const float* Wo = (const float*)d_in[4];
  float* out = (float*)d_out;
  float* fstate = out + (size_t)16777216; // B*T*D

  char* ws = (char*)d_ws;
  u16* x_hi = (u16*)(ws + 0);           // later aliased as att
  u16* x_lo = (u16*)(ws + 33554432);    // later aliased as intra
  u16* qb   = (u16*)(ws + 67108864);
  u16* kb   = (u16*)(ws + 100663296);
  u16* vb   = (u16*)(ws + 134217728);
  u16* wq_h = (u16*)(ws + 167772160);
  u16* wk_h = (u16*)(ws + 176160768);
  u16* wk_l = (u16*)(ws + 184549376);
  u16* wv_h = (u16*)(ws + 192937984);
  u16* wv_l = (u16*)(ws + 201326592);
  u16* wo_h = (u16*)(ws + 209715200);
  unsigned long long* kpk = (unsigned long long*)(ws + 218103808);
  unsigned long long* vpk = (unsigned long long*)(ws + 220200960);
  u16* att   = x_hi;   // x_hi dead after projections
  u16* intra = x_lo;   // x_lo dead after projections

  split_kernel<<<2048, 256, 0, stream>>>(x,  x_hi, x_lo, 16777216);
  split_kernel<<<1024, 256, 0, stream>>>(Wq, wq_h, nullptr, 4194304);
  split_kernel<<<1024, 256, 0, stream>>>(Wk, wk_h, wk_l, 4194304);
  split_kernel<<<1024, 256, 0, stream>>>(Wv, wv_h, wv_l, 4194304);
  split_kernel<<<1024, 256, 0, stream>>>(Wo, wo_h, nullptr, 4194304);

  dim3 gg(16, 64); // N/128, M/128
  gemm_bt<1,0><<<gg, 256, 0, stream>>>(x_hi, nullptr, wq_h, nullptr, qb, nullptr, 8192, 2048, 2048);
  gemm_bt<3,1><<<gg, 256, 0, stream>>>(x_hi, x_lo, wk_h, wk_l, kb, nullptr, 8192, 2048, 2048);
  gemm_bt<3,1><<<gg, 256, 0, stream>>>(x_hi, x_lo, wv_h, wv_l, vb, nullptr, 8192, 2048, 2048);

  pack_signs<<<2048, 128, 0, stream>>>(kb, vb, kpk, vpk);
  intra_kernel<<<2048, 256, 0, stream>>>(qb, kb, vpk, intra);
  state_cross<<<128, 256, 0, stream>>>(qb, kpk, vpk, intra, att, fstate);

  gemm_bt<1,2><<<gg, 256, 0, stream>>>(att, nullptr, wo_h, nullptr, nullptr, out, 8192, 2048, 2048);
}

// Round 2
// 884.741 us; speedup vs baseline: 1.0675x; 1.0675x over previous
//
#include <hip/hip_runtime.h>
#include <stdint.h>

typedef __attribute__((ext_vector_type(8))) short short8;
typedef __attribute__((ext_vector_type(4))) float f32x4;
typedef unsigned short u16;

// ---- helpers ----
__device__ __forceinline__ u16 f2bf(float f) {
  uint32_t u = __builtin_bit_cast(uint32_t, f);
  u = (u + 0x7FFFu + ((u >> 16) & 1u)) >> 16;
  return (u16)u;
}
__device__ __forceinline__ float bf2f(u16 h) {
  uint32_t u = ((uint32_t)h) << 16;
  return __builtin_bit_cast(float, u);
}
__device__ __forceinline__ void lds16(const u16* g, u16* l) {
  __builtin_amdgcn_global_load_lds(
      (const __attribute__((address_space(1))) void*)g,
      (__attribute__((address_space(3))) void*)l, 16, 0, 0);
}
// LDS XOR swizzles on u16 indices (16B granule): involutions.
__device__ __forceinline__ int sw256(int i) { return i ^ (((i >> 7) & 7) << 3); }
__device__ __forceinline__ int sw128(int i) { return i ^ (((i >> 6) & 7) << 3); }

// ---- split f32 -> bf16 hi (+ optional lo) ----
__global__ void split_kernel(const float* __restrict__ in, u16* __restrict__ hi,
                             u16* __restrict__ lo, int n) {
  int i = blockIdx.x * blockDim.x + threadIdx.x;
  int stride = gridDim.x * blockDim.x;
  for (; i < n; i += stride) {
    float v = in[i];
    u16 h = f2bf(v);
    hi[i] = h;
    if (lo) lo[i] = f2bf(v - bf2f(h));
  }
}

// ---- GEMM: C[m][n] = sum_k A[m][k]*B[n][k]  (A: MxK, B: NxK, both row-major bf16)
// SPLIT=1: hi only. SPLIT=3: hi*hi + hi*lo + lo*hi (fp32-ish precision).
// EPI 0: bf16 (b,h,t,d) layout, *qscale    (Q)
// EPI 1: sign -> +-1 bf16, (b,h,t,d) layout (K,V)
// EPI 2: f32 row-major MxN                  (final out)
template<int SPLIT, int EPI>
__global__ __launch_bounds__(256) void gemm_bt(
    const u16* __restrict__ Ahi, const u16* __restrict__ Alo,
    const u16* __restrict__ Bhi, const u16* __restrict__ Blo,
    u16* __restrict__ outb, float* __restrict__ outf,
    int Mdim, int Ndim, int Kdim)
{
  __shared__ __align__(16) u16 sAh[128*32];
  __shared__ __align__(16) u16 sBh[128*32];
  __shared__ __align__(16) u16 sAl[(SPLIT>1)?128*32:8];
  __shared__ __align__(16) u16 sBl[(SPLIT>1)?128*32:8];
  const int t = threadIdx.x;
  const int l = t & 63, w = t >> 6;
  const int wm = w >> 1, wn = w & 1;
  const int m0 = blockIdx.y * 128, n0 = blockIdx.x * 128;
  const int srow = t >> 2, scol = (t & 3) * 8;
  const int fr = l & 15, fc8 = (l >> 4) * 8;

  f32x4 acc[4][4] = {};

  for (int k0 = 0; k0 < Kdim; k0 += 32) {
#pragma unroll
    for (int i = 0; i < 2; i++) {
      size_t ga = (size_t)(m0 + i*64 + srow) * Kdim + k0 + scol;
      size_t gb = (size_t)(n0 + i*64 + srow) * Kdim + k0 + scol;
      lds16(Ahi + ga, sAh + i*2048 + t*8);
      lds16(Bhi + gb, sBh + i*2048 + t*8);
      if constexpr (SPLIT > 1) {
        lds16(Alo + ga, sAl + i*2048 + t*8);
        lds16(Blo + gb, sBl + i*2048 + t*8);
      }
    }
    __syncthreads();
    short8 ah[4], bh[4], al[4], bl[4];
#pragma unroll
    for (int f = 0; f < 4; f++) {
      ah[f] = *(const short8*)(sAh + (wm*64 + f*16 + fr)*32 + fc8);
      bh[f] = *(const short8*)(sBh + (wn*64 + f*16 + fr)*32 + fc8);
      if constexpr (SPLIT > 1) {
        al[f] = *(const short8*)(sAl + (wm*64 + f*16 + fr)*32 + fc8);
        bl[f] = *(const short8*)(sBl + (wn*64 + f*16 + fr)*32 + fc8);
      }
    }
#pragma unroll
    for (int fm = 0; fm < 4; fm++)
#pragma unroll
      for (int fn = 0; fn < 4; fn++) {
        acc[fm][fn] = __builtin_amdgcn_mfma_f32_16x16x32_bf16(ah[fm], bh[fn], acc[fm][fn], 0, 0, 0);
        if constexpr (SPLIT > 1) {
          acc[fm][fn] = __builtin_amdgcn_mfma_f32_16x16x32_bf16(ah[fm], bl[fn], acc[fm][fn], 0, 0, 0);
          acc[fm][fn] = __builtin_amdgcn_mfma_f32_16x16x32_bf16(al[fm], bh[fn], acc[fm][fn], 0, 0, 0);
        }
      }
    __syncthreads();
  }

  const float qscale = 0.08838834764831843f; // 1/sqrt(128)
#pragma unroll
  for (int fm = 0; fm < 4; fm++)
#pragma unroll
    for (int fn = 0; fn < 4; fn++)
#pragma unroll
      for (int r = 0; r < 4; r++) {
        int gm = m0 + wm*64 + fm*16 + (l>>4)*4 + r;
        int gn = n0 + wn*64 + fn*16 + (l & 15);
        float val = acc[fm][fn][r];
        if constexpr (EPI == 2) {
          outf[(size_t)gm * Ndim + gn] = val;
        } else {
          int b = gm >> 12, tt = gm & 4095, h = gn >> 7, dd = gn & 127;
          size_t idx = (((size_t)(b*16 + h))*4096 + tt)*128 + dd;
          if constexpr (EPI == 0) outb[idx] = f2bf(val * qscale);
          else                    outb[idx] = (val >= 0.f) ? (u16)0x3F80 : (u16)0xBF80;
        }
      }
}

// ---- pack sign bits over chunk dim: word[d] bit c = sign(k[b,h,n*64+c,d]) ----
__global__ void pack_signs(const u16* __restrict__ k, const u16* __restrict__ v,
                           unsigned long long* __restrict__ kp, unsigned long long* __restrict__ vp) {
  const int blk = blockIdx.x;            // (b*16+h)*64 + n
  const int d = threadIdx.x;             // 0..127
  const int bh = blk >> 6, n = blk & 63;
  size_t base = (((size_t)bh * 4096) + n * 64) * 128 + d;
  unsigned long long kw = 0, vw = 0;
  for (int c = 0; c < 64; c++) {
    kw |= (unsigned long long)(k[base + (size_t)c*128] >> 15) << c;
    vw |= (unsigned long long)(v[base + (size_t)c*128] >> 15) << c;
  }
  kp[(size_t)blk * 128 + d] = kw;
  vp[(size_t)blk * 128 + d] = vw;
}

// ---- parallel exact prefix-state: stride-8 int16 checkpoints + final state ----
// block = (bh, e-pair); thread = (eloc, d). All exact integer math.
__global__ __launch_bounds__(256) void scan_kernel(
    const unsigned long long* __restrict__ kp, const unsigned long long* __restrict__ vp,
    short* __restrict__ pfx8, float* __restrict__ fsT)
{
  const int t = threadIdx.x;
  const int bh = blockIdx.x >> 6, ep = blockIdx.x & 63;
  const int e = ep * 2 + (t >> 7), d = t & 127;
  const size_t base = (size_t)bh * 64 * 128;
  int s = 0;
  for (int n = 0; n < 64; n++) {
    if ((n & 7) == 0)
      pfx8[((size_t)(bh*8 + (n>>3))*128 + e)*128 + d] = (short)s;
    unsigned long long kw = kp[base + (size_t)n*128 + d];
    unsigned long long vw = vp[base + (size_t)n*128 + e];
    s += 64 - 2*__popcll(kw ^ vw);
  }
  fsT[((size_t)bh*128 + e)*128 + d] = (float)s;  // [bh][e][d] scratch (coalesced)
}

// ---- transpose fsT [bh][e][d] -> fstate [bh][d][e] ----
__global__ __launch_bounds__(256) void transpose_fs(const float* __restrict__ fsT,
                                                    float* __restrict__ fstate) {
  __shared__ float tile[32*130];
  const int t = threadIdx.x;
  const int bh = blockIdx.x >> 2, es = (blockIdx.x & 3) * 32;
#pragma unroll
  for (int i = 0; i < 16; i++) {
    int idx = t + i*256;
    int e2 = idx >> 7, d = idx & 127;
    tile[e2*130 + d] = fsT[((size_t)bh*128 + es + e2)*128 + d];
  }
  __syncthreads();
#pragma unroll
  for (int i = 0; i < 16; i++) {
    int idx = t + i*256;
    int d = idx >> 5, e2 = idx & 31;
    fstate[((size_t)bh*128 + d)*128 + es + e2] = tile[e2*130 + d];
  }
}

// ---- fused intra + cross per (b,h,chunk): fully parallel over 2048 blocks ----
// intra = (QK^T masked) V ; cross = q @ prefix, prefix rebuilt exactly from
// stride-8 checkpoint + <=7 popcount chunk updates; state fed to MFMA as 32*hi+lo.
__global__ __launch_bounds__(256) void fused_attn(
    const u16* __restrict__ q, const u16* __restrict__ k,
    const unsigned long long* __restrict__ kp, const unsigned long long* __restrict__ vp,
    const short* __restrict__ pfx8, u16* __restrict__ att)
{
  __shared__ __align__(16) u16 smem[28672];  // 56KB
  u16* sQ  = smem;          // [64][128] sw256 (q rows)
  u16* sP1 = smem + 8192;   // sK [64][128] sw256 -> sPThi [64][128] sw256
  u16* sP2 = smem + 16384;  // sVt [128][64] sw128 -> sPTlo [64][128] sw256
  u16* sS  = smem + 24576;  // [64][64] sw128

  const int t = threadIdx.x, l = t & 63, w = t >> 6;
  const int blk = blockIdx.x, bh = blk >> 6, n = blk & 63;
  const int b = bh >> 4, hh = bh & 15;
  const int fr = l & 15, fs = l >> 4;
  const size_t qbase = (((size_t)bh * 4096) + n * 64) * 128;
  const size_t pbase = (size_t)bh * 64 * 128;

  // phase A: stage Q,K (pre-swizzled source -> linear LDS dest), unpack V^T
#pragma unroll
  for (int i = 0; i < 4; i++) {
    int arow = i*16 + (t>>4);
    int aslot = (t & 15) ^ (arow & 7);
    size_t g = qbase + (size_t)arow*128 + aslot*8;
    lds16(q + g, sQ + i*2048 + t*8);
    lds16(k + g, sP1 + i*2048 + t*8);
  }
  {
    int d = t >> 1, ch = (t & 1) * 32;
    unsigned long long wv = vp[pbase + (size_t)n*128 + d];
#pragma unroll
    for (int c = 0; c < 32; c += 2) {
      uint32_t b0 = ((wv >> (ch + c)) & 1ull)     ? 0xBF80u : 0x3F80u;
      uint32_t b1 = ((wv >> (ch + c + 1)) & 1ull) ? 0xBF80u : 0x3F80u;
      int li = d*64 + ch + c;
      *(uint32_t*)(sP2 + sw128(li)) = b0 | (b1 << 16);
    }
  }
  __syncthreads();

  // phase B: scores = Q K^T, causal mask, -> sS (bf16)
  f32x4 accS[4] = {};
#pragma unroll
  for (int kk = 0; kk < 4; kk++) {
    int la = (w*16 + fr)*128 + kk*32 + fs*8;
    short8 a = *(const short8*)(sQ + sw256(la));
#pragma unroll
    for (int fn = 0; fn < 4; fn++) {
      int lb = (fn*16 + fr)*128 + kk*32 + fs*8;
      short8 bb = *(const short8*)(sP1 + sw256(lb));
      accS[fn] = __builtin_amdgcn_mfma_f32_16x16x32_bf16(a, bb, accS[fn], 0, 0, 0);
    }
  }
#pragma unroll
  for (int fn = 0; fn < 4; fn++)
#pragma unroll
    for (int r = 0; r < 4; r++) {
      int i = w*16 + fs*4 + r, j = fn*16 + fr;
      float val = (j <= i) ? accS[fn][r] : 0.f;
      sS[sw128(i*64 + j)] = f2bf(val);
    }
  __syncthreads();

  // phase C: intra = sS @ V
  f32x4 accI[8] = {};
#pragma unroll
  for (int kk = 0; kk < 2; kk++) {
    int la = (w*16 + fr)*64 + kk*32 + fs*8;
    short8 a = *(const short8*)(sS + sw128(la));
#pragma unroll
    for (int fn = 0; fn < 8; fn++) {
      int lb = (fn*16 + fr)*64 + kk*32 + fs*8;
      short8 bb = *(const short8*)(sP2 + sw128(lb));
      accI[fn] = __builtin_amdgcn_mfma_f32_16x16x32_bf16(a, bb, accI[fn], 0, 0, 0);
    }
  }
  __syncthreads();

  // cross term, two e-halves; prefix rebuilt exactly per half
  const int m0 = n & ~7, cnt = n & 7;
  for (int hf = 0; hf < 2; hf++) {
    // build sPThi/sPTlo (overwrites sK/sVt regions; reads done at barriers above)
#pragma unroll
    for (int p = 0; p < 4; p++) {
      int erow = p*16 + (t>>4);
      int e = hf*64 + erow;
      const short* ps = pfx8 + ((size_t)(bh*8 + (n>>3))*128 + e)*128 + (t&15)*8;
      short8 pv = *(const short8*)ps;
      int accj[8];
#pragma unroll
      for (int j = 0; j < 8; j++) accj[j] = pv[j];
      for (int m = 0; m < cnt; m++) {
        unsigned long long vw = vp[pbase + (size_t)(m0+m)*128 + e];
#pragma unroll
        for (int j = 0; j < 8; j++) {
          unsigned long long kw = kp[pbase + (size_t)(m0+m)*128 + (t&15)*8 + j];
          accj[j] += 64 - 2*__popcll(kw ^ vw);
        }
      }
      short8 hi, lo;
#pragma unroll
      for (int j = 0; j < 8; j++) {
        hi[j] = (short)f2bf((float)(accj[j] >> 5));
        lo[j] = (short)f2bf((float)(accj[j] & 31));
      }
      int pi = sw256(erow*128 + (t&15)*8);
      *(short8*)(sP1 + pi) = hi;
      *(short8*)(sP2 + pi) = lo;
    }
    __syncthreads();

    f32x4 acch[4] = {}, accl[4] = {};
#pragma unroll
    for (int kk = 0; kk < 4; kk++) {
      int la = (w*16 + fr)*128 + kk*32 + fs*8;
      short8 a = *(const short8*)(sQ + sw256(la));
#pragma unroll
      for (int fn = 0; fn < 4; fn++) {
        int pb = sw256((fn*16 + fr)*128 + kk*32 + fs*8);
        acch[fn] = __builtin_amdgcn_mfma_f32_16x16x32_bf16(a, *(const short8*)(sP1 + pb), acch[fn], 0, 0, 0);
        accl[fn] = __builtin_amdgcn_mfma_f32_16x16x32_bf16(a, *(const short8*)(sP2 + pb), accl[fn], 0, 0, 0);
      }
    }
    // epilogue: att = intra + 32*hi + lo for this e-half
#pragma unroll
    for (int fn = 0; fn < 4; fn++)
#pragma unroll
      for (int r = 0; r < 4; r++) {
        int c = w*16 + fs*4 + r;
        int dcol = hf*64 + fn*16 + fr;
        float val = accI[hf*4+fn][r] + 32.f*acch[fn][r] + accl[fn][r];
        size_t idx = ((size_t)(b*4096 + n*64 + c))*2048 + hh*128 + dcol;
        att[idx] = f2bf(val);
      }
    __syncthreads();  // before next half overwrites sP1/sP2
  }
}

extern "C" void kernel_launch(void* const* d_in, const int* in_sizes, int n_in,
                              void* d_out, int out_size, void* d_ws, size_t ws_size,
                              hipStream_t stream) {
  (void)in_sizes; (void)n_in; (void)out_size; (void)ws_size;
  const float* x  = (const float*)d_in[0];
  const float* Wq = (const float*)d_in[1];
  const float* Wk = (const float*)d_in[2];
  const float* Wv = (const float*)d_in[3];
  const float* Wo = (const float*)d_in[4];
  float* out = (float*)d_out;
  float* fstate = out + (size_t)16777216; // B*T*D

  char* ws = (char*)d_ws;
  u16* x_hi = (u16*)(ws + 0);           // later aliased as att
  u16* x_lo = (u16*)(ws + 33554432);    // later aliased as fsT
  u16* qb   = (u16*)(ws + 67108864);
  u16* kb   = (u16*)(ws + 100663296);
  u16* vb   = (u16*)(ws + 134217728);   // later aliased as pfx8
  u16* wq_h = (u16*)(ws + 167772160);
  u16* wk_h = (u16*)(ws + 176160768);
  u16* wk_l = (u16*)(ws + 184549376);
  u16* wv_h = (u16*)(ws + 192937984);
  u16* wv_l = (u16*)(ws + 201326592);
  u16* wo_h = (u16*)(ws + 209715200);
  unsigned long long* kpk = (unsigned long long*)(ws + 218103808);
  unsigned long long* vpk = (unsigned long long*)(ws + 220200960);
  u16* att    = x_hi;                   // x_hi dead after projections
  float* fsT  = (float*)(ws + 33554432);// x_lo dead after K/V gemms
  short* pfx8 = (short*)(ws + 134217728); // vb dead after pack_signs

  split_kernel<<<2048, 256, 0, stream>>>(x,  x_hi, x_lo, 16777216);
  split_kernel<<<1024, 256, 0, stream>>>(Wq, wq_h, nullptr, 4194304);
  split_kernel<<<1024, 256, 0, stream>>>(Wk, wk_h, wk_l, 4194304);
  split_kernel<<<1024, 256, 0, stream>>>(Wv, wv_h, wv_l, 4194304);
  split_kernel<<<1024, 256, 0, stream>>>(Wo, wo_h, nullptr, 4194304);

  dim3 gg(16, 64); // N/128, M/128
  gemm_bt<1,0><<<gg, 256, 0, stream>>>(x_hi, nullptr, wq_h, nullptr, qb, nullptr, 8192, 2048, 2048);
  gemm_bt<3,1><<<gg, 256, 0, stream>>>(x_hi, x_lo, wk_h, wk_l, kb, nullptr, 8192, 2048, 2048);
  gemm_bt<3,1><<<gg, 256, 0, stream>>>(x_hi, x_lo, wv_h, wv_l, vb, nullptr, 8192, 2048, 2048);

  pack_signs<<<2048, 128, 0, stream>>>(kb, vb, kpk, vpk);
  scan_kernel<<<2048, 256, 0, stream>>>(kpk, vpk, pfx8, fsT);
  transpose_fs<<<128, 256, 0, stream>>>(fsT, fstate);
  fused_attn<<<2048, 256, 0, stream>>>(qb, kb, kpk, vpk, pfx8, att);

  gemm_bt<1,2><<<gg, 256, 0, stream>>>(att, nullptr, wo_h, nullptr, nullptr, out, 8192, 2048, 2048);
}

// Round 3
// 829.230 us; speedup vs baseline: 1.1389x; 1.0669x over previous
//
#include <hip/hip_runtime.h>
#include <stdint.h>

typedef __attribute__((ext_vector_type(8))) short short8;
typedef __attribute__((ext_vector_type(4))) float f32x4;
typedef unsigned short u16;

// ---- helpers ----
__device__ __forceinline__ u16 f2bf(float f) {
  uint32_t u = __builtin_bit_cast(uint32_t, f);
  u = (u + 0x7FFFu + ((u >> 16) & 1u)) >> 16;
  return (u16)u;
}
__device__ __forceinline__ float bf2f(u16 h) {
  uint32_t u = ((uint32_t)h) << 16;
  return __builtin_bit_cast(float, u);
}
__device__ __forceinline__ void lds16(const u16* g, u16* l) {
  __builtin_amdgcn_global_load_lds(
      (const __attribute__((address_space(1))) void*)g,
      (__attribute__((address_space(3))) void*)l, 16, 0, 0);
}
// LDS XOR swizzles on u16 indices (16B granule): involutions.
__device__ __forceinline__ int sw256(int i) { return i ^ (((i >> 7) & 7) << 3); }
__device__ __forceinline__ int sw128(int i) { return i ^ (((i >> 6) & 7) << 3); }

// ---- split f32 -> bf16 hi (+ optional lo) ----
__global__ void split_kernel(const float* __restrict__ in, u16* __restrict__ hi,
                             u16* __restrict__ lo, int n) {
  int i = blockIdx.x * blockDim.x + threadIdx.x;
  int stride = gridDim.x * blockDim.x;
  for (; i < n; i += stride) {
    float v = in[i];
    u16 h = f2bf(v);
    hi[i] = h;
    if (lo) lo[i] = f2bf(v - bf2f(h));
  }
}

// ---- GEMM: C[m][n] = sum_k A[m][k]*B[n][k]  (A: MxK, B: NxK, both row-major bf16)
// 2-phase pipelined (T3-minimum): double-buffered LDS, next tile's
// global_load_lds issued BEFORE current tile's MFMA, ONE barrier per K-step
// (its implicit vmcnt(0)/lgkmcnt(0) drain covers both prefetch + LDS reuse).
// SPLIT=1: hi only. SPLIT=3: hi*hi + hi*lo + lo*hi (fp32-ish precision).
// EPI 0: bf16 (b,h,t,d) layout, *qscale    (Q)
// EPI 1: sign -> +-1 bf16, (b,h,t,d) layout (K,V)
// EPI 2: f32 row-major MxN                  (final out)
template<int SPLIT, int EPI>
__global__ __launch_bounds__(256) void gemm_bt(
    const u16* __restrict__ Ahi, const u16* __restrict__ Alo,
    const u16* __restrict__ Bhi, const u16* __restrict__ Blo,
    u16* __restrict__ outb, float* __restrict__ outf,
    int Mdim, int Ndim, int Kdim)
{
  __shared__ __align__(16) u16 sAh[2][128*32];
  __shared__ __align__(16) u16 sBh[2][128*32];
  __shared__ __align__(16) u16 sAl[(SPLIT>1)?2:1][(SPLIT>1)?128*32:8];
  __shared__ __align__(16) u16 sBl[(SPLIT>1)?2:1][(SPLIT>1)?128*32:8];
  const int t = threadIdx.x;
  const int l = t & 63, w = t >> 6;
  const int wm = w >> 1, wn = w & 1;
  const int m0 = blockIdx.y * 128, n0 = blockIdx.x * 128;
  const int srow = t >> 2, scol = (t & 3) * 8;
  const int fr = l & 15, fc8 = (l >> 4) * 8;

  f32x4 acc[4][4] = {};

  auto STAGE = [&](int buf, int k0) {
#pragma unroll
    for (int i = 0; i < 2; i++) {
      size_t ga = (size_t)(m0 + i*64 + srow) * Kdim + k0 + scol;
      size_t gb = (size_t)(n0 + i*64 + srow) * Kdim + k0 + scol;
      lds16(Ahi + ga, &sAh[buf][i*2048 + t*8]);
      lds16(Bhi + gb, &sBh[buf][i*2048 + t*8]);
      if constexpr (SPLIT > 1) {
        lds16(Alo + ga, &sAl[buf][i*2048 + t*8]);
        lds16(Blo + gb, &sBl[buf][i*2048 + t*8]);
      }
    }
  };

  STAGE(0, 0);
  __syncthreads();
  int cur = 0;

  for (int k0 = 0; k0 < Kdim; k0 += 32) {
    if (k0 + 32 < Kdim) STAGE(cur ^ 1, k0 + 32);   // prefetch flies under MFMA
    short8 ah[4], bh[4], al[4], bl[4];
#pragma unroll
    for (int f = 0; f < 4; f++) {
      ah[f] = *(const short8*)(&sAh[cur][(wm*64 + f*16 + fr)*32 + fc8]);
      bh[f] = *(const short8*)(&sBh[cur][(wn*64 + f*16 + fr)*32 + fc8]);
      if constexpr (SPLIT > 1) {
        al[f] = *(const short8*)(&sAl[cur][(wm*64 + f*16 + fr)*32 + fc8]);
        bl[f] = *(const short8*)(&sBl[cur][(wn*64 + f*16 + fr)*32 + fc8]);
      }
    }
#pragma unroll
    for (int fm = 0; fm < 4; fm++)
#pragma unroll
      for (int fn = 0; fn < 4; fn++) {
        acc[fm][fn] = __builtin_amdgcn_mfma_f32_16x16x32_bf16(ah[fm], bh[fn], acc[fm][fn], 0, 0, 0);
        if constexpr (SPLIT > 1) {
          acc[fm][fn] = __builtin_amdgcn_mfma_f32_16x16x32_bf16(ah[fm], bl[fn], acc[fm][fn], 0, 0, 0);
          acc[fm][fn] = __builtin_amdgcn_mfma_f32_16x16x32_bf16(al[fm], bh[fn], acc[fm][fn], 0, 0, 0);
        }
      }
    __syncthreads();   // drains prefetch vmcnt + fences LDS reuse, one barrier/step
    cur ^= 1;
  }

  const float qscale = 0.08838834764831843f; // 1/sqrt(128)
#pragma unroll
  for (int fm = 0; fm < 4; fm++)
#pragma unroll
    for (int fn = 0; fn < 4; fn++)
#pragma unroll
      for (int r = 0; r < 4; r++) {
        int gm = m0 + wm*64 + fm*16 + (l>>4)*4 + r;
        int gn = n0 + wn*64 + fn*16 + (l & 15);
        float val = acc[fm][fn][r];
        if constexpr (EPI == 2) {
          outf[(size_t)gm * Ndim + gn] = val;
        } else {
          int b = gm >> 12, tt = gm & 4095, h = gn >> 7, dd = gn & 127;
          size_t idx = (((size_t)(b*16 + h))*4096 + tt)*128 + dd;
          if constexpr (EPI == 0) outb[idx] = f2bf(val * qscale);
          else                    outb[idx] = (val >= 0.f) ? (u16)0x3F80 : (u16)0xBF80;
        }
      }
}

// ---- pack sign bits over chunk dim: word[d] bit c = sign(k[b,h,n*64+c,d]) ----
__global__ void pack_signs(const u16* __restrict__ k, const u16* __restrict__ v,
                           unsigned long long* __restrict__ kp, unsigned long long* __restrict__ vp) {
  const int blk = blockIdx.x;            // (b*16+h)*64 + n
  const int d = threadIdx.x;             // 0..127
  const int bh = blk >> 6, n = blk & 63;
  size_t base = (((size_t)bh * 4096) + n * 64) * 128 + d;
  unsigned long long kw = 0, vw = 0;
  for (int c = 0; c < 64; c++) {
    kw |= (unsigned long long)(k[base + (size_t)c*128] >> 15) << c;
    vw |= (unsigned long long)(v[base + (size_t)c*128] >> 15) << c;
  }
  kp[(size_t)blk * 128 + d] = kw;
  vp[(size_t)blk * 128 + d] = vw;
}

// ---- parallel exact prefix-state: stride-8 int16 checkpoints + final state ----
__global__ __launch_bounds__(256) void scan_kernel(
    const unsigned long long* __restrict__ kp, const unsigned long long* __restrict__ vp,
    short* __restrict__ pfx8, float* __restrict__ fsT)
{
  const int t = threadIdx.x;
  const int bh = blockIdx.x >> 6, ep = blockIdx.x & 63;
  const int e = ep * 2 + (t >> 7), d = t & 127;
  const size_t base = (size_t)bh * 64 * 128;
  int s = 0;
  for (int n = 0; n < 64; n++) {
    if ((n & 7) == 0)
      pfx8[((size_t)(bh*8 + (n>>3))*128 + e)*128 + d] = (short)s;
    unsigned long long kw = kp[base + (size_t)n*128 + d];
    unsigned long long vw = vp[base + (size_t)n*128 + e];
    s += 64 - 2*__popcll(kw ^ vw);
  }
  fsT[((size_t)bh*128 + e)*128 + d] = (float)s;  // [bh][e][d] scratch (coalesced)
}

// ---- transpose fsT [bh][e][d] -> fstate [bh][d][e] ----
__global__ __launch_bounds__(256) void transpose_fs(const float* __restrict__ fsT,
                                                    float* __restrict__ fstate) {
  __shared__ float tile[32*130];
  const int t = threadIdx.x;
  const int bh = blockIdx.x >> 2, es = (blockIdx.x & 3) * 32;
#pragma unroll
  for (int i = 0; i < 16; i++) {
    int idx = t + i*256;
    int e2 = idx >> 7, d = idx & 127;
    tile[e2*130 + d] = fsT[((size_t)bh*128 + es + e2)*128 + d];
  }
  __syncthreads();
#pragma unroll
  for (int i = 0; i < 16; i++) {
    int idx = t + i*256;
    int d = idx >> 5, e2 = idx & 31;
    fstate[((size_t)bh*128 + d)*128 + es + e2] = tile[e2*130 + d];
  }
}

// ---- fused intra + cross per (b,h,chunk): fully parallel over 2048 blocks ----
__global__ __launch_bounds__(256) void fused_attn(
    const u16* __restrict__ q, const u16* __restrict__ k,
    const unsigned long long* __restrict__ kp, const unsigned long long* __restrict__ vp,
    const short* __restrict__ pfx8, u16* __restrict__ att)
{
  __shared__ __align__(16) u16 smem[28672];  // 56KB
  u16* sQ  = smem;          // [64][128] sw256 (q rows)
  u16* sP1 = smem + 8192;   // sK [64][128] sw256 -> sPThi [64][128] sw256
  u16* sP2 = smem + 16384;  // sVt [128][64] sw128 -> sPTlo [64][128] sw256
  u16* sS  = smem + 24576;  // [64][64] sw128

  const int t = threadIdx.x, l = t & 63, w = t >> 6;
  const int blk = blockIdx.x, bh = blk >> 6, n = blk & 63;
  const int b = bh >> 4, hh = bh & 15;
  const int fr = l & 15, fs = l >> 4;
  const size_t qbase = (((size_t)bh * 4096) + n * 64) * 128;
  const size_t pbase = (size_t)bh * 64 * 128;

  // phase A: stage Q,K (pre-swizzled source -> linear LDS dest), unpack V^T
#pragma unroll
  for (int i = 0; i < 4; i++) {
    int arow = i*16 + (t>>4);
    int aslot = (t & 15) ^ (arow & 7);
    size_t g = qbase + (size_t)arow*128 + aslot*8;
    lds16(q + g, sQ + i*2048 + t*8);
    lds16(k + g, sP1 + i*2048 + t*8);
  }
  {
    int d = t >> 1, ch = (t & 1) * 32;
    unsigned long long wv = vp[pbase + (size_t)n*128 + d];
#pragma unroll
    for (int c = 0; c < 32; c += 2) {
      uint32_t b0 = ((wv >> (ch + c)) & 1ull)     ? 0xBF80u : 0x3F80u;
      uint32_t b1 = ((wv >> (ch + c + 1)) & 1ull) ? 0xBF80u : 0x3F80u;
      int li = d*64 + ch + c;
      *(uint32_t*)(sP2 + sw128(li)) = b0 | (b1 << 16);
    }
  }
  __syncthreads();

  // phase B: scores = Q K^T, causal mask, -> sS (bf16)
  f32x4 accS[4] = {};
#pragma unroll
  for (int kk = 0; kk < 4; kk++) {
    int la = (w*16 + fr)*128 + kk*32 + fs*8;
    short8 a = *(const short8*)(sQ + sw256(la));
#pragma unroll
    for (int fn = 0; fn < 4; fn++) {
      int lb = (fn*16 + fr)*128 + kk*32 + fs*8;
      short8 bb = *(const short8*)(sP1 + sw256(lb));
      accS[fn] = __builtin_amdgcn_mfma_f32_16x16x32_bf16(a, bb, accS[fn], 0, 0, 0);
    }
  }
#pragma unroll
  for (int fn = 0; fn < 4; fn++)
#pragma unroll
    for (int r = 0; r < 4; r++) {
      int i = w*16 + fs*4 + r, j = fn*16 + fr;
      float val = (j <= i) ? accS[fn][r] : 0.f;
      sS[sw128(i*64 + j)] = f2bf(val);
    }
  __syncthreads();

  // phase C: intra = sS @ V
  f32x4 accI[8] = {};
#pragma unroll
  for (int kk = 0; kk < 2; kk++) {
    int la = (w*16 + fr)*64 + kk*32 + fs*8;
    short8 a = *(const short8*)(sS + sw128(la));
#pragma unroll
    for (int fn = 0; fn < 8; fn++) {
      int lb = (fn*16 + fr)*64 + kk*32 + fs*8;
      short8 bb = *(const short8*)(sP2 + sw128(lb));
      accI[fn] = __builtin_amdgcn_mfma_f32_16x16x32_bf16(a, bb, accI[fn], 0, 0, 0);
    }
  }
  __syncthreads();

  // cross term, two e-halves; prefix rebuilt exactly per half
  const int m0 = n & ~7, cnt = n & 7;
  for (int hf = 0; hf < 2; hf++) {
#pragma unroll
    for (int p = 0; p < 4; p++) {
      int erow = p*16 + (t>>4);
      int e = hf*64 + erow;
      const short* ps = pfx8 + ((size_t)(bh*8 + (n>>3))*128 + e)*128 + (t&15)*8;
      short8 pv = *(const short8*)ps;
      int accj[8];
#pragma unroll
      for (int j = 0; j < 8; j++) accj[j] = pv[j];
      for (int m = 0; m < cnt; m++) {
        unsigned long long vw = vp[pbase + (size_t)(m0+m)*128 + e];
#pragma unroll
        for (int j = 0; j < 8; j++) {
          unsigned long long kw = kp[pbase + (size_t)(m0+m)*128 + (t&15)*8 + j];
          accj[j] += 64 - 2*__popcll(kw ^ vw);
        }
      }
      short8 hi, lo;
#pragma unroll
      for (int j = 0; j < 8; j++) {
        hi[j] = (short)f2bf((float)(accj[j] >> 5));
        lo[j] = (short)f2bf((float)(accj[j] & 31));
      }
      int pi = sw256(erow*128 + (t&15)*8);
      *(short8*)(sP1 + pi) = hi;
      *(short8*)(sP2 + pi) = lo;
    }
    __syncthreads();

    f32x4 acch[4] = {}, accl[4] = {};
#pragma unroll
    for (int kk = 0; kk < 4; kk++) {
      int la = (w*16 + fr)*128 + kk*32 + fs*8;
      short8 a = *(const short8*)(sQ + sw256(la));
#pragma unroll
      for (int fn = 0; fn < 4; fn++) {
        int pb = sw256((fn*16 + fr)*128 + kk*32 + fs*8);
        acch[fn] = __builtin_amdgcn_mfma_f32_16x16x32_bf16(a, *(const short8*)(sP1 + pb), acch[fn], 0, 0, 0);
        accl[fn] = __builtin_amdgcn_mfma_f32_16x16x32_bf16(a, *(const short8*)(sP2 + pb), accl[fn], 0, 0, 0);
      }
    }
#pragma unroll
    for (int fn = 0; fn < 4; fn++)
#pragma unroll
      for (int r = 0; r < 4; r++) {
        int c = w*16 + fs*4 + r;
        int dcol = hf*64 + fn*16 + fr;
        float val = accI[hf*4+fn][r] + 32.f*acch[fn][r] + accl[fn][r];
        size_t idx = ((size_t)(b*4096 + n*64 + c))*2048 + hh*128 + dcol;
        att[idx] = f2bf(val);
      }
    __syncthreads();  // before next half overwrites sP1/sP2
  }
}

extern "C" void kernel_launch(void* const* d_in, const int* in_sizes, int n_in,
                              void* d_out, int out_size, void* d_ws, size_t ws_size,
                              hipStream_t stream) {
  (void)in_sizes; (void)n_in; (void)out_size; (void)ws_size;
  const float* x  = (const float*)d_in[0];
  const float* Wq = (const float*)d_in[1];
  const float* Wk = (const float*)d_in[2];
  const float* Wv = (const float*)d_in[3];
  const float* Wo = (const float*)d_in[4];
  float* out = (float*)d_out;
  float* fstate = out + (size_t)16777216; // B*T*D

  char* ws = (char*)d_ws;
  u16* x_hi = (u16*)(ws + 0);           // later aliased as att
  u16* x_lo = (u16*)(ws + 33554432);    // later aliased as fsT
  u16* qb   = (u16*)(ws + 67108864);
  u16* kb   = (u16*)(ws + 100663296);
  u16* vb   = (u16*)(ws + 134217728);   // later aliased as pfx8
  u16* wq_h = (u16*)(ws + 167772160);
  u16* wk_h = (u16*)(ws + 176160768);
  u16* wk_l = (u16*)(ws + 184549376);
  u16* wv_h = (u16*)(ws + 192937984);
  u16* wv_l = (u16*)(ws + 201326592);
  u16* wo_h = (u16*)(ws + 209715200);
  unsigned long long* kpk = (unsigned long long*)(ws + 218103808);
  unsigned long long* vpk = (unsigned long long*)(ws + 220200960);
  u16* att    = x_hi;                   // x_hi dead after projections
  float* fsT  = (float*)(ws + 33554432);// x_lo dead after K/V gemms
  short* pfx8 = (short*)(ws + 134217728); // vb dead after pack_signs

  split_kernel<<<2048, 256, 0, stream>>>(x,  x_hi, x_lo, 16777216);
  split_kernel<<<1024, 256, 0, stream>>>(Wq, wq_h, nullptr, 4194304);
  split_kernel<<<1024, 256, 0, stream>>>(Wk, wk_h, wk_l, 4194304);
  split_kernel<<<1024, 256, 0, stream>>>(Wv, wv_h, wv_l, 4194304);
  split_kernel<<<1024, 256, 0, stream>>>(Wo, wo_h, nullptr, 4194304);

  dim3 gg(16, 64); // N/128, M/128
  gemm_bt<1,0><<<gg, 256, 0, stream>>>(x_hi, nullptr, wq_h, nullptr, qb, nullptr, 8192, 2048, 2048);
  gemm_bt<3,1><<<gg, 256, 0, stream>>>(x_hi, x_lo, wk_h, wk_l, kb, nullptr, 8192, 2048, 2048);
  gemm_bt<3,1><<<gg, 256, 0, stream>>>(x_hi, x_lo, wv_h, wv_l, vb, nullptr, 8192, 2048, 2048);

  pack_signs<<<2048, 128, 0, stream>>>(kb, vb, kpk, vpk);
  scan_kernel<<<2048, 256, 0, stream>>>(kpk, vpk, pfx8, fsT);
  transpose_fs<<<128, 256, 0, stream>>>(fsT, fstate);
  fused_attn<<<2048, 256, 0, stream>>>(qb, kb, kpk, vpk, pfx8, att);

  gemm_bt<1,2><<<gg, 256, 0, stream>>>(att, nullptr, wo_h, nullptr, nullptr, out, 8192, 2048, 2048);
}

// Round 4
// 750.025 us; speedup vs baseline: 1.2592x; 1.1056x over previous
//
#include <hip/hip_runtime.h>
#include <stdint.h>

typedef __attribute__((ext_vector_type(8))) short short8;
typedef __attribute__((ext_vector_type(4))) float f32x4;
typedef unsigned short u16;

// ---- helpers ----
__device__ __forceinline__ u16 f2bf(float f) {
  uint32_t u = __builtin_bit_cast(uint32_t, f);
  u = (u + 0x7FFFu + ((u >> 16) & 1u)) >> 16;
  return (u16)u;
}
__device__ __forceinline__ float bf2f(u16 h) {
  uint32_t u = ((uint32_t)h) << 16;
  return __builtin_bit_cast(float, u);
}
__device__ __forceinline__ void lds16(const u16* g, u16* l) {
  __builtin_amdgcn_global_load_lds(
      (const __attribute__((address_space(1))) void*)g,
      (__attribute__((address_space(3))) void*)l, 16, 0, 0);
}
// LDS XOR swizzles on u16 indices (16B granule): involutions.
__device__ __forceinline__ int sw256(int i) { return i ^ (((i >> 7) & 7) << 3); }
__device__ __forceinline__ int sw128(int i) { return i ^ (((i >> 6) & 7) << 3); }
// tile-row swizzles: BK=64 rows (64 u16 wide): flip slot bits[5:3] by row&7
__device__ __forceinline__ int swzA64(int i) { return i ^ (((i >> 6) & 7) << 3); }
// BK=32 rows (32 u16 wide): flip slot bits[4:3] by (row>>1)&3
__device__ __forceinline__ int swzA32(int i) { return i ^ (((i >> 6) & 3) << 3); }

// ---- split f32 -> bf16 hi (+ optional lo) ----
__global__ void split_kernel(const float* __restrict__ in, u16* __restrict__ hi,
                             u16* __restrict__ lo, int n) {
  int i = blockIdx.x * blockDim.x + threadIdx.x;
  int stride = gridDim.x * blockDim.x;
  for (; i < n; i += stride) {
    float v = in[i];
    u16 h = f2bf(v);
    hi[i] = h;
    if (lo) lo[i] = f2bf(v - bf2f(h));
  }
}

// ==== 8-phase 256x256 GEMM: C[m][n] = sum_k A[m][k]*B[n][k] ====
// 8 waves (2M x 4N), per-wave 128x64 out. SPLIT=1: BK=64; SPLIT=3: BK=32
// (hi*hi + hi*lo + lo*hi). Double-buffered 128KiB LDS; quarter-granular
// staging units; counted vmcnt(4) at phases 4/8 only (never 0 in loop).
// EPI 0: bf16 (b,h,t,d), *qscale | EPI 1: sign->+-1 bf16 (b,h,t,d) | EPI 2: f32 MxN
template<int SPLIT, int EPI>
__global__ __launch_bounds__(512, 2) void gemm8p(
    const u16* __restrict__ Ahi, const u16* __restrict__ Alo,
    const u16* __restrict__ Bhi, const u16* __restrict__ Blo,
    u16* __restrict__ outb, float* __restrict__ outf,
    int Mdim, int Ndim, int Kdim)
{
  constexpr int BK   = (SPLIT > 1) ? 32 : 64;
  constexpr int KS   = BK / 32;
  constexpr int TILE = 256 * BK;                 // u16 per matrix tile
  constexpr int NMAT = (SPLIT > 1) ? 4 : 2;
  constexpr int AOFF_H = 0;
  constexpr int AOFF_L = (SPLIT > 1) ? TILE : 0;
  constexpr int BOFF_H = (SPLIT > 1) ? 2*TILE : TILE;
  constexpr int BOFF_L = (SPLIT > 1) ? 3*TILE : 0;
  __shared__ __align__(16) u16 smem[2 * NMAT * TILE];   // 128 KiB

  const int t = threadIdx.x, l = t & 63, w = t >> 6;
  const int wm = w >> 2, wn = w & 3;
  const int fr = l & 15, fs = l >> 4;
  // XCD-bijective block swizzle (256 blocks % 8 == 0)
  const int sb = (blockIdx.x & 7) * 32 + (blockIdx.x >> 3);
  const int m0 = (sb >> 3) * 256, n0 = (sb & 7) * 256;
  const int NT = Kdim / BK;

#define SWZ(i) ((BK == 64) ? swzA64(i) : swzA32(i))

  auto STAGE = [&](int unit, int kt) {   // unit: 0=A-even,1=B-even,2=A-odd,3=B-odd
    if (kt >= NT) return;
    const int bufb = (kt & 1) * NMAT * TILE;
    const int k0 = kt * BK;
    const bool isB = unit & 1;
    const int odd = unit >> 1;
    const int g0 = isB ? n0 : m0;
    if constexpr (SPLIT == 1) {
      const u16* src = isB ? Bhi : Ahi;
      const int mb = bufb + (isB ? BOFF_H : AOFF_H);
#pragma unroll
      for (int i = 0; i < 2; i++) {
        int L = i * 512 + t;
        int d = isB ? (((L >> 8) << 12) + ((L & 255) << 3) + (odd << 11))
                    : (((L >> 9) << 13) + ((L & 511) << 3) + (odd << 12));
        int r = d >> 6, s = (d >> 3) & 7;
        lds16(src + (size_t)(g0 + r) * Kdim + k0 + ((s ^ (r & 7)) << 3), smem + mb + d);
      }
    } else {
      const u16* sh = isB ? Bhi : Ahi;
      const u16* sl = isB ? Blo : Alo;
      const int mh = bufb + (isB ? BOFF_H : AOFF_H);
      int d = isB ? (((t >> 7) << 11) + ((t & 127) << 3) + (odd << 10))
                  : (((t >> 8) << 12) + ((t & 255) << 3) + (odd << 11));
      int r = d >> 5, s = (d >> 3) & 3;
      size_t g = (size_t)(g0 + r) * Kdim + k0 + ((s ^ ((r >> 1) & 3)) << 3);
      lds16(sh + g, smem + mh + d);
      lds16(sl + g, smem + mh + TILE + d);
    }
  };

  f32x4 acc[8][4] = {};

#define PHASE(KT, Q, UNIT, SKT, VM) {                                          \
  const int bufb_ = ((KT) & 1) * NMAT * TILE;                                  \
  short8 rah[4][KS], ral[4][KS], rbh[2][KS], rbl[2][KS];                       \
  _Pragma("unroll") for (int fm = 0; fm < 4; fm++)                             \
    _Pragma("unroll") for (int ks = 0; ks < KS; ks++) {                        \
      int ia = (wm*128 + ((Q)>>1)*64 + fm*16 + fr)*BK + ks*32 + fs*8;          \
      rah[fm][ks] = *(const short8*)(smem + bufb_ + AOFF_H + SWZ(ia));         \
      if constexpr (SPLIT > 1)                                                 \
        ral[fm][ks] = *(const short8*)(smem + bufb_ + AOFF_L + SWZ(ia));       \
    }                                                                          \
  _Pragma("unroll") for (int fn = 0; fn < 2; fn++)                             \
    _Pragma("unroll") for (int ks = 0; ks < KS; ks++) {                        \
      int ib = (wn*64 + ((Q)&1)*32 + fn*16 + fr)*BK + ks*32 + fs*8;            \
      rbh[fn][ks] = *(const short8*)(smem + bufb_ + BOFF_H + SWZ(ib));         \
      if constexpr (SPLIT > 1)                                                 \
        rbl[fn][ks] = *(const short8*)(smem + bufb_ + BOFF_L + SWZ(ib));       \
    }                                                                          \
  STAGE((UNIT), (SKT));                                                        \
  if constexpr (VM) {                                                          \
    if ((SKT) < NT) asm volatile("s_waitcnt vmcnt(4)" ::: "memory");           \
    else            asm volatile("s_waitcnt vmcnt(0)" ::: "memory");           \
  }                                                                            \
  __builtin_amdgcn_s_barrier();                                                \
  asm volatile("s_waitcnt lgkmcnt(0)" ::: "memory");                           \
  __builtin_amdgcn_sched_barrier(0);                                           \
  __builtin_amdgcn_s_setprio(1);                                               \
  _Pragma("unroll") for (int fm = 0; fm < 4; fm++)                             \
    _Pragma("unroll") for (int fn = 0; fn < 2; fn++)                           \
      _Pragma("unroll") for (int ks = 0; ks < KS; ks++) {                      \
        f32x4& A = acc[((Q)>>1)*4 + fm][((Q)&1)*2 + fn];                       \
        A = __builtin_amdgcn_mfma_f32_16x16x32_bf16(rah[fm][ks], rbh[fn][ks], A, 0,0,0); \
        if constexpr (SPLIT > 1) {                                             \
          A = __builtin_amdgcn_mfma_f32_16x16x32_bf16(rah[fm][ks], rbl[fn][ks], A, 0,0,0); \
          A = __builtin_amdgcn_mfma_f32_16x16x32_bf16(ral[fm][ks], rbh[fn][ks], A, 0,0,0); \
        }                                                                      \
      }                                                                        \
  __builtin_amdgcn_s_setprio(0);                                               \
  __builtin_amdgcn_sched_barrier(0);                                           \
  __builtin_amdgcn_s_barrier();                                                \
}

  // prologue: T0 complete + T1 A-even,B-even; keep T1 halves in flight
  STAGE(0, 0); STAGE(1, 0); STAGE(2, 0); STAGE(3, 0);
  STAGE(0, 1); STAGE(1, 1);
  asm volatile("s_waitcnt vmcnt(4)" ::: "memory");
  __builtin_amdgcn_s_barrier();

  const int LI = NT >> 1;
  for (int i = 0; i < LI; i++) {
    const int Ta = 2*i, Tb = 2*i + 1;
    PHASE(Ta, 0, 2, Tb,   0)   // stage Tb.A-odd   -> buf1
    PHASE(Ta, 1, 3, Tb,   0)   // stage Tb.B-odd   -> buf1
    PHASE(Ta, 2, 0, Ta+2, 0)   // stage Ta+2.A-even-> buf0 (A-even freed ph2)
    PHASE(Ta, 3, 1, Ta+2, 1)   // stage Ta+2.B-even-> buf0; vmcnt(4): Tb landed
    PHASE(Tb, 0, 2, Ta+2, 0)   // stage Ta+2.A-odd -> buf0
    PHASE(Tb, 1, 3, Ta+2, 0)   // stage Ta+2.B-odd -> buf0
    PHASE(Tb, 2, 0, Tb+2, 0)   // stage Tb+2.A-even-> buf1
    PHASE(Tb, 3, 1, Tb+2, 1)   // stage Tb+2.B-even-> buf1; vmcnt(4): Ta+2 landed
  }
#undef PHASE
#undef SWZ

  const float qscale = 0.08838834764831843f; // 1/sqrt(128)
#pragma unroll
  for (int fm = 0; fm < 8; fm++)
#pragma unroll
    for (int fn = 0; fn < 4; fn++)
#pragma unroll
      for (int r = 0; r < 4; r++) {
        int gm = m0 + wm*128 + fm*16 + fs*4 + r;
        int gn = n0 + wn*64 + fn*16 + fr;
        float val = acc[fm][fn][r];
        if constexpr (EPI == 2) {
          outf[(size_t)gm * Ndim + gn] = val;
        } else {
          int b = gm >> 12, tt = gm & 4095, h = gn >> 7, dd = gn & 127;
          size_t idx = (((size_t)(b*16 + h))*4096 + tt)*128 + dd;
          if constexpr (EPI == 0) outb[idx] = f2bf(val * qscale);
          else                    outb[idx] = (val >= 0.f) ? (u16)0x3F80 : (u16)0xBF80;
        }
      }
}

// ---- pack sign bits over chunk dim: word[d] bit c = sign(k[b,h,n*64+c,d]) ----
__global__ void pack_signs(const u16* __restrict__ k, const u16* __restrict__ v,
                           unsigned long long* __restrict__ kp, unsigned long long* __restrict__ vp) {
  const int blk = blockIdx.x;            // (b*16+h)*64 + n
  const int d = threadIdx.x;             // 0..127
  const int bh = blk >> 6, n = blk & 63;
  size_t base = (((size_t)bh * 4096) + n * 64) * 128 + d;
  unsigned long long kw = 0, vw = 0;
  for (int c = 0; c < 64; c++) {
    kw |= (unsigned long long)(k[base + (size_t)c*128] >> 15) << c;
    vw |= (unsigned long long)(v[base + (size_t)c*128] >> 15) << c;
  }
  kp[(size_t)blk * 128 + d] = kw;
  vp[(size_t)blk * 128 + d] = vw;
}

// ---- parallel exact prefix-state: stride-8 int16 checkpoints + final state ----
__global__ __launch_bounds__(256) void scan_kernel(
    const unsigned long long* __restrict__ kp, const unsigned long long* __restrict__ vp,
    short* __restrict__ pfx8, float* __restrict__ fsT)
{
  const int t = threadIdx.x;
  const int bh = blockIdx.x >> 6, ep = blockIdx.x & 63;
  const int e = ep * 2 + (t >> 7), d = t & 127;
  const size_t base = (size_t)bh * 64 * 128;
  int s = 0;
  for (int n = 0; n < 64; n++) {
    if ((n & 7) == 0)
      pfx8[((size_t)(bh*8 + (n>>3))*128 + e)*128 + d] = (short)s;
    unsigned long long kw = kp[base + (size_t)n*128 + d];
    unsigned long long vw = vp[base + (size_t)n*128 + e];
    s += 64 - 2*__popcll(kw ^ vw);
  }
  fsT[((size_t)bh*128 + e)*128 + d] = (float)s;  // [bh][e][d] scratch (coalesced)
}

// ---- transpose fsT [bh][e][d] -> fstate [bh][d][e] ----
__global__ __launch_bounds__(256) void transpose_fs(const float* __restrict__ fsT,
                                                    float* __restrict__ fstate) {
  __shared__ float tile[32*130];
  const int t = threadIdx.x;
  const int bh = blockIdx.x >> 2, es = (blockIdx.x & 3) * 32;
#pragma unroll
  for (int i = 0; i < 16; i++) {
    int idx = t + i*256;
    int e2 = idx >> 7, d = idx & 127;
    tile[e2*130 + d] = fsT[((size_t)bh*128 + es + e2)*128 + d];
  }
  __syncthreads();
#pragma unroll
  for (int i = 0; i < 16; i++) {
    int idx = t + i*256;
    int d = idx >> 5, e2 = idx & 31;
    fstate[((size_t)bh*128 + d)*128 + es + e2] = tile[e2*130 + d];
  }
}

// ---- fused intra + cross per (b,h,chunk): fully parallel over 2048 blocks ----
__global__ __launch_bounds__(256) void fused_attn(
    const u16* __restrict__ q, const u16* __restrict__ k,
    const unsigned long long* __restrict__ kp, const unsigned long long* __restrict__ vp,
    const short* __restrict__ pfx8, u16* __restrict__ att)
{
  __shared__ __align__(16) u16 smem[28672];  // 56KB
  u16* sQ  = smem;          // [64][128] sw256 (q rows)
  u16* sP1 = smem + 8192;   // sK [64][128] sw256 -> sPThi [64][128] sw256
  u16* sP2 = smem + 16384;  // sVt [128][64] sw128 -> sPTlo [64][128] sw256
  u16* sS  = smem + 24576;  // [64][64] sw128

  const int t = threadIdx.x, l = t & 63, w = t >> 6;
  const int blk = blockIdx.x, bh = blk >> 6, n = blk & 63;
  const int b = bh >> 4, hh = bh & 15;
  const int fr = l & 15, fs = l >> 4;
  const size_t qbase = (((size_t)bh * 4096) + n * 64) * 128;
  const size_t pbase = (size_t)bh * 64 * 128;

  // phase A: stage Q,K (pre-swizzled source -> linear LDS dest), unpack V^T
#pragma unroll
  for (int i = 0; i < 4; i++) {
    int arow = i*16 + (t>>4);
    int aslot = (t & 15) ^ (arow & 7);
    size_t g = qbase + (size_t)arow*128 + aslot*8;
    lds16(q + g, sQ + i*2048 + t*8);
    lds16(k + g, sP1 + i*2048 + t*8);
  }
  {
    int d = t >> 1, ch = (t & 1) * 32;
    unsigned long long wv = vp[pbase + (size_t)n*128 + d];
#pragma unroll
    for (int c = 0; c < 32; c += 2) {
      uint32_t b0 = ((wv >> (ch + c)) & 1ull)     ? 0xBF80u : 0x3F80u;
      uint32_t b1 = ((wv >> (ch + c + 1)) & 1ull) ? 0xBF80u : 0x3F80u;
      int li = d*64 + ch + c;
      *(uint32_t*)(sP2 + sw128(li)) = b0 | (b1 << 16);
    }
  }
  __syncthreads();

  // phase B: scores = Q K^T, causal mask, -> sS (bf16)
  f32x4 accS[4] = {};
#pragma unroll
  for (int kk = 0; kk < 4; kk++) {
    int la = (w*16 + fr)*128 + kk*32 + fs*8;
    short8 a = *(const short8*)(sQ + sw256(la));
#pragma unroll
    for (int fn = 0; fn < 4; fn++) {
      int lb = (fn*16 + fr)*128 + kk*32 + fs*8;
      short8 bb = *(const short8*)(sP1 + sw256(lb));
      accS[fn] = __builtin_amdgcn_mfma_f32_16x16x32_bf16(a, bb, accS[fn], 0, 0, 0);
    }
  }
#pragma unroll
  for (int fn = 0; fn < 4; fn++)
#pragma unroll
    for (int r = 0; r < 4; r++) {
      int i = w*16 + fs*4 + r, j = fn*16 + fr;
      float v = (j <= i) ? accS[fn][r] : 0.f;
      sS[sw128(i*64 + j)] = f2bf(v);
    }
  __syncthreads();

  // phase C: intra = sS @ V
  f32x4 accI[8] = {};
#pragma unroll
  for (int kk = 0; kk < 2; kk++) {
    int la = (w*16 + fr)*64 + kk*32 + fs*8;
    short8 a = *(const short8*)(sS + sw128(la));
#pragma unroll
    for (int fn = 0; fn < 8; fn++) {
      int lb = (fn*16 + fr)*64 + kk*32 + fs*8;
      short8 bb = *(const short8*)(sP2 + sw128(lb));
      accI[fn] = __builtin_amdgcn_mfma_f32_16x16x32_bf16(a, bb, accI[fn], 0, 0, 0);
    }
  }
  __syncthreads();

  // cross term, two e-halves; prefix rebuilt exactly per half
  const int m0 = n & ~7, cnt = n & 7;
  for (int hf = 0; hf < 2; hf++) {
#pragma unroll
    for (int p = 0; p < 4; p++) {
      int erow = p*16 + (t>>4);
      int e = hf*64 + erow;
      const short* ps = pfx8 + ((size_t)(bh*8 + (n>>3))*128 + e)*128 + (t&15)*8;
      short8 pv = *(const short8*)ps;
      int accj[8];
#pragma unroll
      for (int j = 0; j < 8; j++) accj[j] = pv[j];
      for (int m = 0; m < cnt; m++) {
        unsigned long long vw = vp[pbase + (size_t)(m0+m)*128 + e];
#pragma unroll
        for (int j = 0; j < 8; j++) {
          unsigned long long kw = kp[pbase + (size_t)(m0+m)*128 + (t&15)*8 + j];
          accj[j] += 64 - 2*__popcll(kw ^ vw);
        }
      }
      short8 hi, lo;
#pragma unroll
      for (int j = 0; j < 8; j++) {
        hi[j] = (short)f2bf((float)(accj[j] >> 5));
        lo[j] = (short)f2bf((float)(accj[j] & 31));
      }
      int pi = sw256(erow*128 + (t&15)*8);
      *(short8*)(sP1 + pi) = hi;
      *(short8*)(sP2 + pi) = lo;
    }
    __syncthreads();

    f32x4 acch[4] = {}, accl[4] = {};
#pragma unroll
    for (int kk = 0; kk < 4; kk++) {
      int la = (w*16 + fr)*128 + kk*32 + fs*8;
      short8 a = *(const short8*)(sQ + sw256(la));
#pragma unroll
      for (int fn = 0; fn < 4; fn++) {
        int pb = sw256((fn*16 + fr)*128 + kk*32 + fs*8);
        acch[fn] = __builtin_amdgcn_mfma_f32_16x16x32_bf16(a, *(const short8*)(sP1 + pb), acch[fn], 0, 0, 0);
        accl[fn] = __builtin_amdgcn_mfma_f32_16x16x32_bf16(a, *(const short8*)(sP2 + pb), accl[fn], 0, 0, 0);
      }
    }
#pragma unroll
    for (int fn = 0; fn < 4; fn++)
#pragma unroll
      for (int r = 0; r < 4; r++) {
        int c = w*16 + fs*4 + r;
        int dcol = hf*64 + fn*16 + fr;
        float val = accI[hf*4+fn][r] + 32.f*acch[fn][r] + accl[fn][r];
        size_t idx = ((size_t)(b*4096 + n*64 + c))*2048 + hh*128 + dcol;
        att[idx] = f2bf(val);
      }
    __syncthreads();  // before next half overwrites sP1/sP2
  }
}

extern "C" void kernel_launch(void* const* d_in, const int* in_sizes, int n_in,
                              void* d_out, int out_size, void* d_ws, size_t ws_size,
                              hipStream_t stream) {
  (void)in_sizes; (void)n_in; (void)out_size; (void)ws_size;
  const float* x  = (const float*)d_in[0];
  const float* Wq = (const float*)d_in[1];
  const float* Wk = (const float*)d_in[2];
  const float* Wv = (const float*)d_in[3];
  const float* Wo = (const float*)d_in[4];
  float* out = (float*)d_out;
  float* fstate = out + (size_t)16777216; // B*T*D

  char* ws = (char*)d_ws;
  u16* x_hi = (u16*)(ws + 0);           // later aliased as att
  u16* x_lo = (u16*)(ws + 33554432);    // later aliased as fsT
  u16* qb   = (u16*)(ws + 67108864);
  u16* kb   = (u16*)(ws + 100663296);
  u16* vb   = (u16*)(ws + 134217728);   // later aliased as pfx8
  u16* wq_h = (u16*)(ws + 167772160);
  u16* wk_h = (u16*)(ws + 176160768);
  u16* wk_l = (u16*)(ws + 184549376);
  u16* wv_h = (u16*)(ws + 192937984);
  u16* wv_l = (u16*)(ws + 201326592);
  u16* wo_h = (u16*)(ws + 209715200);
  unsigned long long* kpk = (unsigned long long*)(ws + 218103808);
  unsigned long long* vpk = (unsigned long long*)(ws + 220200960);
  u16* att    = x_hi;                   // x_hi dead after projections
  float* fsT  = (float*)(ws + 33554432);// x_lo dead after K/V gemms
  short* pfx8 = (short*)(ws + 134217728); // vb dead after pack_signs

  split_kernel<<<2048, 256, 0, stream>>>(x,  x_hi, x_lo, 16777216);
  split_kernel<<<1024, 256, 0, stream>>>(Wq, wq_h, nullptr, 4194304);
  split_kernel<<<1024, 256, 0, stream>>>(Wk, wk_h, wk_l, 4194304);
  split_kernel<<<1024, 256, 0, stream>>>(Wv, wv_h, wv_l, 4194304);
  split_kernel<<<1024, 256, 0, stream>>>(Wo, wo_h, nullptr, 4194304);

  gemm8p<1,0><<<256, 512, 0, stream>>>(x_hi, nullptr, wq_h, nullptr, qb, nullptr, 8192, 2048, 2048);
  gemm8p<3,1><<<256, 512, 0, stream>>>(x_hi, x_lo, wk_h, wk_l, kb, nullptr, 8192, 2048, 2048);
  gemm8p<3,1><<<256, 512, 0, stream>>>(x_hi, x_lo, wv_h, wv_l, vb, nullptr, 8192, 2048, 2048);

  pack_signs<<<2048, 128, 0, stream>>>(kb, vb, kpk, vpk);
  scan_kernel<<<2048, 256, 0, stream>>>(kpk, vpk, pfx8, fsT);
  transpose_fs<<<128, 256, 0, stream>>>(fsT, fstate);
  fused_attn<<<2048, 256, 0, stream>>>(qb, kb, kpk, vpk, pfx8, att);

  gemm8p<1,2><<<256, 512, 0, stream>>>(att, nullptr, wo_h, nullptr, nullptr, out, 8192, 2048, 2048);
}